// Round 2
// baseline (452.504 us; speedup 1.0000x reference)
//
#include <hip/hip_runtime.h>
#include <stdint.h>

namespace {

constexpr int IN_F = 1024;
constexpr int OUT_F = 1024;
constexpr int GSZ = 8;
constexpr int BM = 128, BN = 128, BK = 64;
constexpr int LDK = BK + 8;               // padded leading dim: row stride 144 B (16B-aligned, 2-way banks)
constexpr int KTOT = IN_F + IN_F * GSZ;   // 9216
constexpr int NT = KTOT / BK;             // 144

constexpr double H_D     = 4.0 / 7.0;                 // grid step
constexpr double INVD_D  = 1.0 / (H_D + 1e-6);        // matches reference exactly
constexpr double L2E_D   = 1.4426950408889634;
constexpr double SQL2E_D = 1.2011224087864498;        // sqrt(log2 e)
constexpr double CS_D    = INVD_D * SQL2E_D;          // exp(-(d*invd)^2) = exp2(-((d*CS)^2))

using short8 = __attribute__((ext_vector_type(8))) short;
using f32x4  = __attribute__((ext_vector_type(4))) float;

// RTNE f32 -> bf16 bits, finite inputs (transparent, no asm / header dependence)
__device__ __forceinline__ unsigned f2bf(float f) {
  unsigned u = __float_as_uint(f);
  return (u + 0x7fffu + ((u >> 16) & 1u)) >> 16;
}
__device__ __forceinline__ unsigned pk2(float lo, float hi) {
  return f2bf(lo) | (f2bf(hi) << 16);
}
__device__ __forceinline__ float silu_f(float v) {
  // v * sigmoid(v) = v / (1 + exp(-v))
  float e = __builtin_amdgcn_exp2f(-v * (float)L2E_D);
  return v * __builtin_amdgcn_rcpf(1.0f + e);
}

__global__ __launch_bounds__(256)
void kan_fused(const float* __restrict__ x, const float* __restrict__ bw,
               const float* __restrict__ bb, const float* __restrict__ sw,
               float* __restrict__ out)
{
  __shared__ unsigned short tA[BM][LDK];   // A tile: 128 rows x 64 k (bf16 bits)
  __shared__ unsigned short tB[BN][LDK];   // B tile: 128 out-cols x 64 k

  const int t    = threadIdx.x;
  const int lane = t & 63;
  const int wid  = t >> 6;
  const int wr   = (wid >> 1) * 64;   // wave row offset in 128x128 tile
  const int wc   = (wid & 1) * 64;    // wave col offset
  const int bm0  = blockIdx.x * BM;
  const int bn0  = blockIdx.y * BN;

  const float CS = (float)CS_D;
  float gsc[GSZ];
#pragma unroll
  for (int g = 0; g < GSZ; ++g)
    gsc[g] = (float)((-2.0 + g * H_D) * CS_D);   // grid_g * CS

  f32x4 acc[4][4];
#pragma unroll
  for (int m = 0; m < 4; ++m)
#pragma unroll
    for (int n = 0; n < 4; ++n) acc[m][n] = (f32x4)0.0f;

  float4 rA[8], rB[8];
  const int rw = t >> 4;            // 0..15
  const int cw = (t & 15) * 4;      // 0,4,...,60  (k position, elements)

  // ---- issue global f32 loads for tile `step` into registers ----
  auto load_tile = [&](int step) {
    const int k0 = step * BK;
    const bool base = (k0 < IN_F);
#pragma unroll
    for (int j = 0; j < 8; ++j) {
      const int row = j * 16 + rw;
      const float* p = base
        ? (bw + (size_t)(bn0 + row) * IN_F + k0 + cw)
        : (sw + (size_t)(bn0 + row) * (size_t)(IN_F * GSZ) + (k0 - IN_F) + cw);
      rB[j] = *(const float4*)p;
    }
    if (base) {
#pragma unroll
      for (int j = 0; j < 8; ++j) {
        const int row = j * 16 + rw;
        rA[j] = *(const float4*)(x + (size_t)(bm0 + row) * IN_F + k0 + cw);
      }
    } else {
      const int i0  = (k0 - IN_F) >> 3;   // first x-column of this tile
      const int row = t >> 1;
      rA[0] = *(const float4*)(x + (size_t)(bm0 + row) * IN_F + i0 + (t & 1) * 4);
    }
  };

  // ---- convert (silu / RBF / f32->bf16) and store tile to LDS ----
  auto store_tile = [&](int step) {
    const int k0 = step * BK;
    const bool base = (k0 < IN_F);
#pragma unroll
    for (int j = 0; j < 8; ++j) {
      const int row = j * 16 + rw;
      uint2 v;
      v.x = pk2(rB[j].x, rB[j].y);
      v.y = pk2(rB[j].z, rB[j].w);
      *(uint2*)&tB[row][cw] = v;
    }
    if (base) {
#pragma unroll
      for (int j = 0; j < 8; ++j) {
        const int row = j * 16 + rw;
        uint2 v;
        v.x = pk2(silu_f(rA[j].x), silu_f(rA[j].y));
        v.y = pk2(silu_f(rA[j].z), silu_f(rA[j].w));
        *(uint2*)&tA[row][cw] = v;
      }
    } else {
      const int row  = t >> 1;
      const int half = t & 1;
      const float* xv = (const float*)&rA[0];
#pragma unroll
      for (int c = 0; c < 4; ++c) {
        const float tb = xv[c] * CS;
        union { unsigned u[4]; int4 v4; } pkv;
#pragma unroll
        for (int g = 0; g < 8; g += 2) {
          const float t0 = tb - gsc[g];
          const float t1 = tb - gsc[g + 1];
          const float e0 = __builtin_amdgcn_exp2f(-(t0 * t0));
          const float e1 = __builtin_amdgcn_exp2f(-(t1 * t1));
          pkv.u[g >> 1] = pk2(e0, e1);
        }
        const int kc = (half * 4 + c) * 8;   // k-local = i_loc*8 + g
        *(int4*)&tA[row][kc] = pkv.v4;
      }
    }
  };

  // ---- MFMA over the staged 128x128x64 tile ----
  auto compute_tile = [&]() {
    const int r  = lane & 15;            // fragment row/col
    const int kq = (lane >> 4) * 8;      // fragment k group (8 contiguous)
#pragma unroll
    for (int kh = 0; kh < 2; ++kh) {
      short8 af[4], bf[4];
#pragma unroll
      for (int m = 0; m < 4; ++m)
        af[m] = *(const short8*)&tA[wr + m * 16 + r][kh * 32 + kq];
#pragma unroll
      for (int n = 0; n < 4; ++n)
        bf[n] = *(const short8*)&tB[wc + n * 16 + r][kh * 32 + kq];
#pragma unroll
      for (int m = 0; m < 4; ++m)
#pragma unroll
        for (int n = 0; n < 4; ++n)
          acc[m][n] = __builtin_amdgcn_mfma_f32_16x16x32_bf16(af[m], bf[n], acc[m][n], 0, 0, 0);
    }
  };

  load_tile(0);
  for (int step = 0; step < NT; ++step) {
    store_tile(step);            // regs -> LDS (single buffer)
    __syncthreads();             // writes visible before reads
    if (step + 1 < NT) load_tile(step + 1);   // global loads overlap MFMA
    compute_tile();
    __syncthreads();             // reads done before next store
  }

  // epilogue: C/D mapping col=lane&15, row=(lane>>4)*4+reg (m89/m91-verified)
  const int col = lane & 15;
  const int rr  = (lane >> 4) * 4;
#pragma unroll
  for (int m = 0; m < 4; ++m) {
    const int gr = bm0 + wr + m * 16 + rr;
#pragma unroll
    for (int n = 0; n < 4; ++n) {
      const int gc = bn0 + wc + n * 16 + col;
      const float bias = bb[gc];
#pragma unroll
      for (int j = 0; j < 4; ++j)
        out[(size_t)(gr + j) * OUT_F + gc] = acc[m][n][j] + bias;
    }
  }
}

} // namespace

extern "C" void kernel_launch(void* const* d_in, const int* in_sizes, int n_in,
                              void* d_out, int out_size, void* d_ws, size_t ws_size,
                              hipStream_t stream) {
  // Expected (setup_inputs dict order): x, base_w, base_b, spline_w.
  // Guard against alphabetical order (base_b, base_w, spline_w, x) via sizes.
  const float *x, *bw, *bb, *sw;
  if (in_sizes[0] == OUT_F) {            // got base_b first -> alphabetical order
    bb = (const float*)d_in[0];
    bw = (const float*)d_in[1];
    sw = (const float*)d_in[2];
    x  = (const float*)d_in[3];
  } else {
    x  = (const float*)d_in[0];
    bw = (const float*)d_in[1];
    bb = (const float*)d_in[2];
    sw = (const float*)d_in[3];
  }
  float* out = (float*)d_out;

  const int rows = 8192;                 // 4 * 2048
  dim3 grid(rows / BM, OUT_F / BN);      // 64 x 8
  hipLaunchKernelGGL(kan_fused, grid, dim3(256), 0, stream, x, bw, bb, sw, out);
}

// Round 3
// 227.546 us; speedup vs baseline: 1.9886x; 1.9886x over previous
//
#include <hip/hip_runtime.h>
#include <stdint.h>

namespace {

constexpr int IN_F = 1024;
constexpr int OUT_F = 1024;
constexpr int GSZ = 8;
constexpr int KTOT = IN_F + IN_F * GSZ;   // 9216
constexpr int BK = 64;
constexpr int NT = KTOT / BK;             // 144
constexpr int NBASE = IN_F / BK;          // 16 base-path steps

// fast-path geometry
constexpr int BM = 128, BN = 256;
constexpr int NBLK = OUT_F / BN;          // 4
constexpr size_t IMG_BYTES = (size_t)BN * BK * 2;              // 32 KB per (nb,step)
constexpr size_t WS_NEEDED = (size_t)NBLK * NT * IMG_BYTES;    // 18.87 MB

constexpr double H_D     = 4.0 / 7.0;
constexpr double INVD_D  = 1.0 / (H_D + 1e-6);
constexpr double L2E_D   = 1.4426950408889634;
constexpr double SQL2E_D = 1.2011224087864498;       // sqrt(log2 e)
constexpr double CS_D    = INVD_D * SQL2E_D;         // exp(-(d*invd)^2)=exp2(-((d*CS)^2))
constexpr double DLT_D   = H_D * CS_D;               // grid spacing, scaled

using short8 = __attribute__((ext_vector_type(8))) short;
using f32x4  = __attribute__((ext_vector_type(4))) float;

__device__ __forceinline__ unsigned cvt_pk(float lo, float hi) {
  unsigned r;
  asm("v_cvt_pk_bf16_f32 %0, %1, %2" : "=v"(r) : "v"(lo), "v"(hi));
  return r;
}
__device__ __forceinline__ float silu_f(float v) {
  float e = __builtin_amdgcn_exp2f(-v * (float)L2E_D);
  return v * __builtin_amdgcn_rcpf(1.0f + e);
}
// XOR-swizzled byte offset in a [rows][64 bf16] tile, row stride 128B.
__device__ __forceinline__ int swz(int row, int kk) {
  return (row * 128 + kk * 2) ^ ((row & 7) << 4);
}

// ---------------- weight prep: f32 -> bf16, swizzled LDS images ----------------
__global__ void wprep(const float* __restrict__ bw, const float* __restrict__ sw,
                      char* __restrict__ wimg)
{
  const int total = NBLK * NT * BN * 8;   // 16B chunks (8 bf16 each)
  for (int idx = blockIdx.x * blockDim.x + threadIdx.x; idx < total;
       idx += gridDim.x * blockDim.x) {
    const int kk8  = idx & 7;
    const int row  = (idx >> 3) & (BN - 1);
    const int rest = idx >> 11;           // nb*NT + step
    const int step = rest % NT;
    const int nb   = rest / NT;
    const int o    = nb * BN + row;
    const int k    = step * BK + kk8 * 8;
    const float* src = (k < IN_F)
      ? (bw + (size_t)o * IN_F + k)
      : (sw + (size_t)o * (size_t)(IN_F * GSZ) + (k - IN_F));
    const float4 a = ((const float4*)src)[0];
    const float4 b = ((const float4*)src)[1];
    int4 v;
    v.x = (int)cvt_pk(a.x, a.y);
    v.y = (int)cvt_pk(a.z, a.w);
    v.z = (int)cvt_pk(b.x, b.y);
    v.w = (int)cvt_pk(b.z, b.w);
    *(int4*)(wimg + (size_t)rest * IMG_BYTES + swz(row, kk8 * 8)) = v;
  }
}

// ---------------- fast main kernel: 128x256 tile, 8 waves ----------------
__global__ __launch_bounds__(512)
void kan_fast(const float* __restrict__ x, const float* __restrict__ bb,
              const char* __restrict__ wimg, float* __restrict__ out)
{
  __shared__ char tA[BM * BK * 2];        // 16 KB, swizzled
  __shared__ char tB[2][BN * BK * 2];     // 2 x 32 KB, swizzled (baked in image)

  const int t    = threadIdx.x;
  const int lane = t & 63;
  const int wid  = t >> 6;
  const int wr   = (wid >> 2) * 64;       // 2 wave-rows
  const int wc   = (wid & 3) * 64;        // 4 wave-cols
  const int bm0  = blockIdx.y * BM;
  const char* img = wimg + (size_t)blockIdx.x * NT * IMG_BYTES;
  const int bn0  = blockIdx.x * BN;

  const float CSf  = (float)CS_D;
  const float C0f  = (float)(-2.0 * CS_D);       // leftmost grid point, scaled
  const float TDLT = (float)(2.0 * DLT_D);
  float Kc[7];
#pragma unroll
  for (int g = 0; g < 7; ++g) {
    const double cg  = (-2.0 + g * H_D) * CS_D;
    const double cg1 = (-2.0 + (g + 1) * H_D) * CS_D;
    Kc[g] = __builtin_amdgcn_exp2f((float)(-DLT_D * (cg + cg1)));
  }

  f32x4 acc[4][4];
#pragma unroll
  for (int m = 0; m < 4; ++m)
#pragma unroll
    for (int n = 0; n < 4; ++n) acc[m][n] = (f32x4)0.0f;

  float4 rX[4];

  auto issue_B = [&](int step, int buf) {
    const char* g = img + (size_t)step * IMG_BYTES + t * 16;
    char* l = tB[buf] + t * 16;
#pragma unroll
    for (int j = 0; j < 4; ++j)
      __builtin_amdgcn_global_load_lds(
        (const __attribute__((address_space(1))) void*)(g + j * 8192),
        (__attribute__((address_space(3))) void*)(l + j * 8192), 16, 0, 0);
  };

  auto load_x = [&](int step) {
    const int k0  = step * BK;
    const int row = t >> 2;
    if (k0 < IN_F) {
      const float* p = x + (size_t)(bm0 + row) * IN_F + k0 + (t & 3) * 16;
#pragma unroll
      for (int j = 0; j < 4; ++j) rX[j] = ((const float4*)p)[j];
    } else {
      const int i0 = (k0 - IN_F) >> 3;
      const float2 v = *(const float2*)(x + (size_t)(bm0 + row) * IN_F + i0 + (t & 3) * 2);
      rX[0].x = v.x; rX[0].y = v.y;
    }
  };

  auto store_A = [&](int step) {
    const int row = t >> 2;
    if (step < NBASE) {
      unsigned q[8];
#pragma unroll
      for (int j = 0; j < 4; ++j) {
        q[2 * j]     = cvt_pk(silu_f(rX[j].x), silu_f(rX[j].y));
        q[2 * j + 1] = cvt_pk(silu_f(rX[j].z), silu_f(rX[j].w));
      }
      const int kc0 = (t & 3) * 16;
      *(int4*)(tA + swz(row, kc0))     = make_int4(q[0], q[1], q[2], q[3]);
      *(int4*)(tA + swz(row, kc0 + 8)) = make_int4(q[4], q[5], q[6], q[7]);
    } else {
#pragma unroll
      for (int c = 0; c < 2; ++c) {
        const float xv = c ? rX[0].y : rX[0].x;
        const float tb = xv * CSf;
        const float d0 = tb - C0f;
        float e = __builtin_amdgcn_exp2f(-(d0 * d0));   // e_0
        const float r = __builtin_amdgcn_exp2f(tb * TDLT);
        unsigned q[4];
#pragma unroll
        for (int g = 0; g < 4; ++g) {
          const float a = e;                  // e_{2g}
          const float b = a * r * Kc[2 * g];  // e_{2g+1}
          q[g] = cvt_pk(a, b);
          if (g < 3) e = b * r * Kc[2 * g + 1];
        }
        const int iloc = (t & 3) * 2 + c;
        *(int4*)(tA + swz(row, iloc * 8)) = make_int4(q[0], q[1], q[2], q[3]);
      }
    }
  };

  auto compute = [&](int buf) {
    const int r  = lane & 15;
    const int kq = (lane >> 4) * 8;
#pragma unroll
    for (int kh = 0; kh < 2; ++kh) {
      short8 af[4], bf[4];
#pragma unroll
      for (int m = 0; m < 4; ++m)
        af[m] = *(const short8*)(tA + swz(wr + m * 16 + r, kh * 32 + kq));
#pragma unroll
      for (int n = 0; n < 4; ++n)
        bf[n] = *(const short8*)(tB[buf] + swz(wc + n * 16 + r, kh * 32 + kq));
#pragma unroll
      for (int m = 0; m < 4; ++m)
#pragma unroll
        for (int n = 0; n < 4; ++n)
          acc[m][n] = __builtin_amdgcn_mfma_f32_16x16x32_bf16(af[m], bf[n], acc[m][n], 0, 0, 0);
    }
  };

  issue_B(0, 0);
  load_x(0);
  int cur = 0;
  for (int step = 0; step < NT; ++step) {
    store_A(step);                 // VALU staging from prefetched x regs
    __syncthreads();               // tA visible; B(step) glds drained
    if (step + 1 < NT) {
      issue_B(step + 1, cur ^ 1);  // async, hidden under MFMA phase
      load_x(step + 1);
    }
    compute(cur);
    __syncthreads();               // reads done; next-B glds drained
    cur ^= 1;
  }

  // epilogue: C/D mapping col=lane&15, row=(lane>>4)*4+reg (verified r2)
  const int col = lane & 15;
  const int rr  = (lane >> 4) * 4;
#pragma unroll
  for (int m = 0; m < 4; ++m) {
    const int gr = bm0 + wr + m * 16 + rr;
#pragma unroll
    for (int n = 0; n < 4; ++n) {
      const int gc = bn0 + wc + n * 16 + col;
      const float bias = bb[gc];
#pragma unroll
      for (int j = 0; j < 4; ++j)
        out[(size_t)(gr + j) * OUT_F + gc] = acc[m][n][j] + bias;
    }
  }
}

// ---------------- fallback: round-2 verified kernel (unchanged) ----------------
constexpr int SLDK = 64 + 8;

__device__ __forceinline__ unsigned f2bf(float f) {
  unsigned u = __float_as_uint(f);
  return (u + 0x7fffu + ((u >> 16) & 1u)) >> 16;
}
__device__ __forceinline__ unsigned pk2(float lo, float hi) {
  return f2bf(lo) | (f2bf(hi) << 16);
}

__global__ __launch_bounds__(256)
void kan_slow(const float* __restrict__ x, const float* __restrict__ bw,
              const float* __restrict__ bb, const float* __restrict__ sw,
              float* __restrict__ out)
{
  __shared__ unsigned short tA[128][SLDK];
  __shared__ unsigned short tB[128][SLDK];

  const int t    = threadIdx.x;
  const int lane = t & 63;
  const int wid  = t >> 6;
  const int wr   = (wid >> 1) * 64;
  const int wc   = (wid & 1) * 64;
  const int bm0  = blockIdx.x * 128;
  const int bn0  = blockIdx.y * 128;

  const float CS = (float)CS_D;
  float gsc[GSZ];
#pragma unroll
  for (int g = 0; g < GSZ; ++g)
    gsc[g] = (float)((-2.0 + g * H_D) * CS_D);

  f32x4 acc[4][4];
#pragma unroll
  for (int m = 0; m < 4; ++m)
#pragma unroll
    for (int n = 0; n < 4; ++n) acc[m][n] = (f32x4)0.0f;

  float4 rA[8], rB[8];
  const int rw = t >> 4;
  const int cw = (t & 15) * 4;

  auto load_tile = [&](int step) {
    const int k0 = step * BK;
    const bool base = (k0 < IN_F);
#pragma unroll
    for (int j = 0; j < 8; ++j) {
      const int row = j * 16 + rw;
      const float* p = base
        ? (bw + (size_t)(bn0 + row) * IN_F + k0 + cw)
        : (sw + (size_t)(bn0 + row) * (size_t)(IN_F * GSZ) + (k0 - IN_F) + cw);
      rB[j] = *(const float4*)p;
    }
    if (base) {
#pragma unroll
      for (int j = 0; j < 8; ++j) {
        const int row = j * 16 + rw;
        rA[j] = *(const float4*)(x + (size_t)(bm0 + row) * IN_F + k0 + cw);
      }
    } else {
      const int i0  = (k0 - IN_F) >> 3;
      const int row = t >> 1;
      rA[0] = *(const float4*)(x + (size_t)(bm0 + row) * IN_F + i0 + (t & 1) * 4);
    }
  };

  auto store_tile = [&](int step) {
    const int k0 = step * BK;
    const bool base = (k0 < IN_F);
#pragma unroll
    for (int j = 0; j < 8; ++j) {
      const int row = j * 16 + rw;
      uint2 v;
      v.x = pk2(rB[j].x, rB[j].y);
      v.y = pk2(rB[j].z, rB[j].w);
      *(uint2*)&tB[row][cw] = v;
    }
    if (base) {
#pragma unroll
      for (int j = 0; j < 8; ++j) {
        const int row = j * 16 + rw;
        uint2 v;
        v.x = pk2(silu_f(rA[j].x), silu_f(rA[j].y));
        v.y = pk2(silu_f(rA[j].z), silu_f(rA[j].w));
        *(uint2*)&tA[row][cw] = v;
      }
    } else {
      const int row  = t >> 1;
      const int half = t & 1;
      const float* xv = (const float*)&rA[0];
#pragma unroll
      for (int c = 0; c < 4; ++c) {
        const float tb = xv[c] * CS;
        union { unsigned u[4]; int4 v4; } pkv;
#pragma unroll
        for (int g = 0; g < 8; g += 2) {
          const float t0 = tb - gsc[g];
          const float t1 = tb - gsc[g + 1];
          const float e0 = __builtin_amdgcn_exp2f(-(t0 * t0));
          const float e1 = __builtin_amdgcn_exp2f(-(t1 * t1));
          pkv.u[g >> 1] = pk2(e0, e1);
        }
        const int kc = (half * 4 + c) * 8;
        *(int4*)&tA[row][kc] = pkv.v4;
      }
    }
  };

  auto compute_tile = [&]() {
    const int r  = lane & 15;
    const int kq = (lane >> 4) * 8;
#pragma unroll
    for (int kh = 0; kh < 2; ++kh) {
      short8 af[4], bf[4];
#pragma unroll
      for (int m = 0; m < 4; ++m)
        af[m] = *(const short8*)&tA[wr + m * 16 + r][kh * 32 + kq];
#pragma unroll
      for (int n = 0; n < 4; ++n)
        bf[n] = *(const short8*)&tB[wc + n * 16 + r][kh * 32 + kq];
#pragma unroll
      for (int m = 0; m < 4; ++m)
#pragma unroll
        for (int n = 0; n < 4; ++n)
          acc[m][n] = __builtin_amdgcn_mfma_f32_16x16x32_bf16(af[m], bf[n], acc[m][n], 0, 0, 0);
    }
  };

  load_tile(0);
  for (int step = 0; step < NT; ++step) {
    store_tile(step);
    __syncthreads();
    if (step + 1 < NT) load_tile(step + 1);
    compute_tile();
    __syncthreads();
  }

  const int col = lane & 15;
  const int rr  = (lane >> 4) * 4;
#pragma unroll
  for (int m = 0; m < 4; ++m) {
    const int gr = bm0 + wr + m * 16 + rr;
#pragma unroll
    for (int n = 0; n < 4; ++n) {
      const int gc = bn0 + wc + n * 16 + col;
      const float bias = bb[gc];
#pragma unroll
      for (int j = 0; j < 4; ++j)
        out[(size_t)(gr + j) * OUT_F + gc] = acc[m][n][j] + bias;
    }
  }
}

} // namespace

extern "C" void kernel_launch(void* const* d_in, const int* in_sizes, int n_in,
                              void* d_out, int out_size, void* d_ws, size_t ws_size,
                              hipStream_t stream) {
  const float *x, *bw, *bb, *sw;
  if (in_sizes[0] == OUT_F) {            // alphabetical order guard
    bb = (const float*)d_in[0];
    bw = (const float*)d_in[1];
    sw = (const float*)d_in[2];
    x  = (const float*)d_in[3];
  } else {
    x  = (const float*)d_in[0];
    bw = (const float*)d_in[1];
    bb = (const float*)d_in[2];
    sw = (const float*)d_in[3];
  }
  float* out = (float*)d_out;
  const int rows = (in_sizes[0] == OUT_F) ? in_sizes[3] / IN_F : in_sizes[0] / IN_F;

  if (ws_size >= WS_NEEDED && d_ws != nullptr && (rows % BM) == 0) {
    hipLaunchKernelGGL(wprep, dim3(2048), dim3(256), 0, stream, bw, sw, (char*)d_ws);
    dim3 grid(NBLK, rows / BM);          // N fastest -> per-XCD weight-panel locality
    hipLaunchKernelGGL(kan_fast, grid, dim3(512), 0, stream,
                       x, bb, (const char*)d_ws, out);
  } else {
    dim3 grid(rows / 128, OUT_F / 128);
    hipLaunchKernelGGL(kan_slow, grid, dim3(256), 0, stream, x, bw, bb, sw, out);
  }
}

// Round 4
// 187.676 us; speedup vs baseline: 2.4111x; 1.2124x over previous
//
#include <hip/hip_runtime.h>
#include <stdint.h>

namespace {

constexpr int IN_F = 1024;
constexpr int OUT_F = 1024;
constexpr int GSZ = 8;
constexpr int KTOT = IN_F + IN_F * GSZ;   // 9216
constexpr int BK = 64;
constexpr int NT = KTOT / BK;             // 144 (even)
constexpr int NBASE = IN_F / BK;          // 16 base-path steps

// fast-path geometry
constexpr int BM = 128, BN = 256;
constexpr int NBLK = OUT_F / BN;          // 4
constexpr size_t IMG_BYTES = (size_t)BN * BK * 2;              // 32 KB per (nb,step)
constexpr size_t WS_NEEDED = (size_t)NBLK * NT * IMG_BYTES;    // 18.87 MB

constexpr double H_D     = 4.0 / 7.0;
constexpr double INVD_D  = 1.0 / (H_D + 1e-6);
constexpr double L2E_D   = 1.4426950408889634;
constexpr double SQL2E_D = 1.2011224087864498;       // sqrt(log2 e)
constexpr double CS_D    = INVD_D * SQL2E_D;         // exp(-(d*invd)^2)=exp2(-((d*CS)^2))
constexpr double DLT_D   = H_D * CS_D;               // grid spacing, scaled

using short8 = __attribute__((ext_vector_type(8))) short;
using f32x4  = __attribute__((ext_vector_type(4))) float;

__device__ __forceinline__ unsigned cvt_pk(float lo, float hi) {
  unsigned r;
  asm("v_cvt_pk_bf16_f32 %0, %1, %2" : "=v"(r) : "v"(lo), "v"(hi));
  return r;
}
__device__ __forceinline__ float silu_f(float v) {
  float e = __builtin_amdgcn_exp2f(-v * (float)L2E_D);
  return v * __builtin_amdgcn_rcpf(1.0f + e);
}
// XOR-swizzled byte offset in a [rows][64 bf16] tile, row stride 128B.
__device__ __forceinline__ int swz(int row, int kk) {
  return (row * 128 + kk * 2) ^ ((row & 7) << 4);
}

// ---------------- weight prep: f32 -> bf16, swizzled LDS images ----------------
__global__ void wprep(const float* __restrict__ bw, const float* __restrict__ sw,
                      char* __restrict__ wimg)
{
  const int total = NBLK * NT * BN * 8;   // 16B chunks (8 bf16 each)
  for (int idx = blockIdx.x * blockDim.x + threadIdx.x; idx < total;
       idx += gridDim.x * blockDim.x) {
    const int kk8  = idx & 7;
    const int row  = (idx >> 3) & (BN - 1);
    const int rest = idx >> 11;           // nb*NT + step
    const int step = rest % NT;
    const int nb   = rest / NT;
    const int o    = nb * BN + row;
    const int k    = step * BK + kk8 * 8;
    const float* src = (k < IN_F)
      ? (bw + (size_t)o * IN_F + k)
      : (sw + (size_t)o * (size_t)(IN_F * GSZ) + (k - IN_F));
    const float4 a = ((const float4*)src)[0];
    const float4 b = ((const float4*)src)[1];
    int4 v;
    v.x = (int)cvt_pk(a.x, a.y);
    v.y = (int)cvt_pk(a.z, a.w);
    v.z = (int)cvt_pk(b.x, b.y);
    v.w = (int)cvt_pk(b.z, b.w);
    *(int4*)(wimg + (size_t)rest * IMG_BYTES + swz(row, kk8 * 8)) = v;
  }
}

// ---------------- fast main kernel: 128x256 tile, 8 waves, phased schedule ----------------
__global__ __launch_bounds__(512, 2)
void kan_fast(const float* __restrict__ x, const float* __restrict__ bb,
              const char* __restrict__ wimg, float* __restrict__ out)
{
  __shared__ char tA[2][BM * BK * 2];     // 2 x 16 KB, swizzled
  __shared__ char tB[2][BN * BK * 2];     // 2 x 32 KB, swizzled (baked in image)

  const int t    = threadIdx.x;
  const int lane = t & 63;
  const int wid  = t >> 6;
  const int wr   = (wid >> 2) * 64;       // 2 wave-rows
  const int wc   = (wid & 3) * 64;        // 4 wave-cols
  const int bm0  = blockIdx.y * BM;
  const char* img = wimg + (size_t)blockIdx.x * NT * IMG_BYTES;
  const int bn0  = blockIdx.x * BN;

  const float CSf  = (float)CS_D;
  const float C0f  = (float)(-2.0 * CS_D);
  const float TDLT = (float)(2.0 * DLT_D);
  float Kc[7];
#pragma unroll
  for (int g = 0; g < 7; ++g) {
    const double cg  = (-2.0 + g * H_D) * CS_D;
    const double cg1 = (-2.0 + (g + 1) * H_D) * CS_D;
    Kc[g] = __builtin_amdgcn_exp2f((float)(-DLT_D * (cg + cg1)));
  }

  f32x4 acc[4][4];
#pragma unroll
  for (int m = 0; m < 4; ++m)
#pragma unroll
    for (int n = 0; n < 4; ++n) acc[m][n] = (f32x4)0.0f;

  float4 xE[4], xO[4];                    // ping-pong x prefetch (static indexing only)

  // issue half of B(step) image into dstB: 2 x global_load_lds(16B) per thread
  auto issue_B2 = [&](int step, char* dstB, int half) {
    const char* g = img + (size_t)step * IMG_BYTES + half * 16384 + t * 16;
    char* l = dstB + half * 16384 + t * 16;
#pragma unroll
    for (int j = 0; j < 2; ++j)
      __builtin_amdgcn_global_load_lds(
        (const __attribute__((address_space(1))) void*)(g + j * 8192),
        (__attribute__((address_space(3))) void*)(l + j * 8192), 16, 0, 0);
  };

  auto load_x = [&](int step, float4 (&xr)[4]) {
    const int k0  = step * BK;
    const int row = t >> 2;
    if (k0 < IN_F) {
      const float* p = x + (size_t)(bm0 + row) * IN_F + k0 + (t & 3) * 16;
#pragma unroll
      for (int j = 0; j < 4; ++j) xr[j] = ((const float4*)p)[j];
    } else {
      const int i0 = (k0 - IN_F) >> 3;
      const float2 v = *(const float2*)(x + (size_t)(bm0 + row) * IN_F + i0 + (t & 3) * 2);
      xr[0].x = v.x; xr[0].y = v.y;
    }
  };

  auto conv_A = [&](int step, const float4 (&xr)[4], char* dstA) {
    const int row = t >> 2;
    if (step < NBASE) {
      unsigned q[8];
#pragma unroll
      for (int j = 0; j < 4; ++j) {
        q[2 * j]     = cvt_pk(silu_f(xr[j].x), silu_f(xr[j].y));
        q[2 * j + 1] = cvt_pk(silu_f(xr[j].z), silu_f(xr[j].w));
      }
      const int kc0 = (t & 3) * 16;
      *(int4*)(dstA + swz(row, kc0))     = make_int4(q[0], q[1], q[2], q[3]);
      *(int4*)(dstA + swz(row, kc0 + 8)) = make_int4(q[4], q[5], q[6], q[7]);
    } else {
#pragma unroll
      for (int c = 0; c < 2; ++c) {
        const float xv = c ? xr[0].y : xr[0].x;
        const float tb = xv * CSf;
        const float d0 = tb - C0f;
        float e = __builtin_amdgcn_exp2f(-(d0 * d0));   // e_0
        const float r = __builtin_amdgcn_exp2f(tb * TDLT);
        unsigned q[4];
#pragma unroll
        for (int g = 0; g < 4; ++g) {
          const float a = e;                  // e_{2g}
          const float b = a * r * Kc[2 * g];  // e_{2g+1}
          q[g] = cvt_pk(a, b);
          if (g < 3) e = b * r * Kc[2 * g + 1];
        }
        const int iloc = (t & 3) * 2 + c;
        *(int4*)(dstA + swz(row, iloc * 8)) = make_int4(q[0], q[1], q[2], q[3]);
      }
    }
  };

  auto read_frags = [&](const char* A, const char* B, int kh,
                        short8 (&af)[4], short8 (&bf)[4]) {
    const int r  = lane & 15;
    const int kq = (lane >> 4) * 8;
#pragma unroll
    for (int m = 0; m < 4; ++m)
      af[m] = *(const short8*)(A + swz(wr + m * 16 + r, kh * 32 + kq));
#pragma unroll
    for (int n = 0; n < 4; ++n)
      bf[n] = *(const short8*)(B + swz(wc + n * 16 + r, kh * 32 + kq));
  };

  auto mfma16 = [&](short8 (&af)[4], short8 (&bf)[4]) {
#pragma unroll
    for (int m = 0; m < 4; ++m)
#pragma unroll
      for (int n = 0; n < 4; ++n)
        acc[m][n] = __builtin_amdgcn_mfma_f32_16x16x32_bf16(af[m], bf[n], acc[m][n], 0, 0, 0);
  };

  // one K-step: 2 MFMA phases with barrier/lgkm/setprio discipline
  auto step_body = [&](int s, char* curA, char* curB, char* nxtA, char* nxtB,
                       const float4 (&xconv)[4], float4 (&xload)[4]) {
    // ---- phase 0 (kh=0) ----
    if (s + 1 < NT) issue_B2(s + 1, nxtB, 0);
    if (s + 2 < NT) load_x(s + 2, xload);
    {
      short8 af[4], bf[4];
      read_frags(curA, curB, 0, af, bf);
      __builtin_amdgcn_s_barrier();
      asm volatile("s_waitcnt lgkmcnt(0)" ::: "memory");
      __builtin_amdgcn_sched_barrier(0);
      __builtin_amdgcn_s_setprio(1);
      mfma16(af, bf);
      __builtin_amdgcn_s_setprio(0);
      __builtin_amdgcn_s_barrier();
    }
    // ---- phase 1 (kh=1) ----
    if (s + 1 < NT) {
      issue_B2(s + 1, nxtB, 1);
      conv_A(s + 1, xconv, nxtA);          // VALU staging into the other A buffer
    }
    {
      short8 af[4], bf[4];
      read_frags(curA, curB, 1, af, bf);
      __builtin_amdgcn_s_barrier();
      asm volatile("s_waitcnt lgkmcnt(0)" ::: "memory");
      __builtin_amdgcn_sched_barrier(0);
      __builtin_amdgcn_s_setprio(1);
      mfma16(af, bf);
      __builtin_amdgcn_s_setprio(0);
    }
    __syncthreads();   // vmcnt(0)+lgkmcnt(0)+barrier: publish nxtA/nxtB (glds had ~1 step to land)
  };

  // prologue
  load_x(0, xE);
  load_x(1, xO);
  issue_B2(0, tB[0], 0);
  issue_B2(0, tB[0], 1);
  conv_A(0, xE, tA[0]);
  __syncthreads();

  for (int s = 0; s < NT; s += 2) {
    step_body(s,     tA[0], tB[0], tA[1], tB[1], xO, xE);
    step_body(s + 1, tA[1], tB[1], tA[0], tB[0], xE, xO);
  }

  // epilogue: C/D mapping col=lane&15, row=(lane>>4)*4+reg (verified r2/r3)
  const int col = lane & 15;
  const int rr  = (lane >> 4) * 4;
#pragma unroll
  for (int m = 0; m < 4; ++m) {
    const int gr = bm0 + wr + m * 16 + rr;
#pragma unroll
    for (int n = 0; n < 4; ++n) {
      const int gc = bn0 + wc + n * 16 + col;
      const float bias = bb[gc];
#pragma unroll
      for (int j = 0; j < 4; ++j)
        out[(size_t)(gr + j) * OUT_F + gc] = acc[m][n][j] + bias;
    }
  }
}

// ---------------- fallback: round-2 verified kernel (unchanged) ----------------
constexpr int SLDK = 64 + 8;

__device__ __forceinline__ unsigned f2bf(float f) {
  unsigned u = __float_as_uint(f);
  return (u + 0x7fffu + ((u >> 16) & 1u)) >> 16;
}
__device__ __forceinline__ unsigned pk2(float lo, float hi) {
  return f2bf(lo) | (f2bf(hi) << 16);
}

__global__ __launch_bounds__(256)
void kan_slow(const float* __restrict__ x, const float* __restrict__ bw,
              const float* __restrict__ bb, const float* __restrict__ sw,
              float* __restrict__ out)
{
  __shared__ unsigned short tA[128][SLDK];
  __shared__ unsigned short tB[128][SLDK];

  const int t    = threadIdx.x;
  const int lane = t & 63;
  const int wid  = t >> 6;
  const int wr   = (wid >> 1) * 64;
  const int wc   = (wid & 1) * 64;
  const int bm0  = blockIdx.x * 128;
  const int bn0  = blockIdx.y * 128;

  const float CS = (float)CS_D;
  float gsc[GSZ];
#pragma unroll
  for (int g = 0; g < GSZ; ++g)
    gsc[g] = (float)((-2.0 + g * H_D) * CS_D);

  f32x4 acc[4][4];
#pragma unroll
  for (int m = 0; m < 4; ++m)
#pragma unroll
    for (int n = 0; n < 4; ++n) acc[m][n] = (f32x4)0.0f;

  float4 rA[8], rB[8];
  const int rw = t >> 4;
  const int cw = (t & 15) * 4;

  auto load_tile = [&](int step) {
    const int k0 = step * BK;
    const bool base = (k0 < IN_F);
#pragma unroll
    for (int j = 0; j < 8; ++j) {
      const int row = j * 16 + rw;
      const float* p = base
        ? (bw + (size_t)(bn0 + row) * IN_F + k0 + cw)
        : (sw + (size_t)(bn0 + row) * (size_t)(IN_F * GSZ) + (k0 - IN_F) + cw);
      rB[j] = *(const float4*)p;
    }
    if (base) {
#pragma unroll
      for (int j = 0; j < 8; ++j) {
        const int row = j * 16 + rw;
        rA[j] = *(const float4*)(x + (size_t)(bm0 + row) * IN_F + k0 + cw);
      }
    } else {
      const int i0  = (k0 - IN_F) >> 3;
      const int row = t >> 1;
      rA[0] = *(const float4*)(x + (size_t)(bm0 + row) * IN_F + i0 + (t & 1) * 4);
    }
  };

  auto store_tile = [&](int step) {
    const int k0 = step * BK;
    const bool base = (k0 < IN_F);
#pragma unroll
    for (int j = 0; j < 8; ++j) {
      const int row = j * 16 + rw;
      uint2 v;
      v.x = pk2(rB[j].x, rB[j].y);
      v.y = pk2(rB[j].z, rB[j].w);
      *(uint2*)&tB[row][cw] = v;
    }
    if (base) {
#pragma unroll
      for (int j = 0; j < 8; ++j) {
        const int row = j * 16 + rw;
        uint2 v;
        v.x = pk2(silu_f(rA[j].x), silu_f(rA[j].y));
        v.y = pk2(silu_f(rA[j].z), silu_f(rA[j].w));
        *(uint2*)&tA[row][cw] = v;
      }
    } else {
      const int row  = t >> 1;
      const int half = t & 1;
      const float* xv = (const float*)&rA[0];
#pragma unroll
      for (int c = 0; c < 4; ++c) {
        const float tb = xv[c] * CS;
        union { unsigned u[4]; int4 v4; } pkv;
#pragma unroll
        for (int g = 0; g < 8; g += 2) {
          const float t0 = tb - gsc[g];
          const float t1 = tb - gsc[g + 1];
          const float e0 = __builtin_amdgcn_exp2f(-(t0 * t0));
          const float e1 = __builtin_amdgcn_exp2f(-(t1 * t1));
          pkv.u[g >> 1] = pk2(e0, e1);
        }
        const int kc = (half * 4 + c) * 8;
        *(int4*)&tA[row][kc] = pkv.v4;
      }
    }
  };

  auto compute_tile = [&]() {
    const int r  = lane & 15;
    const int kq = (lane >> 4) * 8;
#pragma unroll
    for (int kh = 0; kh < 2; ++kh) {
      short8 af[4], bf[4];
#pragma unroll
      for (int m = 0; m < 4; ++m)
        af[m] = *(const short8*)&tA[wr + m * 16 + r][kh * 32 + kq];
#pragma unroll
      for (int n = 0; n < 4; ++n)
        bf[n] = *(const short8*)&tB[wc + n * 16 + r][kh * 32 + kq];
#pragma unroll
      for (int m = 0; m < 4; ++m)
#pragma unroll
        for (int n = 0; n < 4; ++n)
          acc[m][n] = __builtin_amdgcn_mfma_f32_16x16x32_bf16(af[m], bf[n], acc[m][n], 0, 0, 0);
    }
  };

  load_tile(0);
  for (int step = 0; step < NT; ++step) {
    store_tile(step);
    __syncthreads();
    if (step + 1 < NT) load_tile(step + 1);
    compute_tile();
    __syncthreads();
  }

  const int col = lane & 15;
  const int rr  = (lane >> 4) * 4;
#pragma unroll
  for (int m = 0; m < 4; ++m) {
    const int gr = bm0 + wr + m * 16 + rr;
#pragma unroll
    for (int n = 0; n < 4; ++n) {
      const int gc = bn0 + wc + n * 16 + col;
      const float bias = bb[gc];
#pragma unroll
      for (int j = 0; j < 4; ++j)
        out[(size_t)(gr + j) * OUT_F + gc] = acc[m][n][j] + bias;
    }
  }
}

} // namespace

extern "C" void kernel_launch(void* const* d_in, const int* in_sizes, int n_in,
                              void* d_out, int out_size, void* d_ws, size_t ws_size,
                              hipStream_t stream) {
  const float *x, *bw, *bb, *sw;
  if (in_sizes[0] == OUT_F) {            // alphabetical order guard
    bb = (const float*)d_in[0];
    bw = (const float*)d_in[1];
    sw = (const float*)d_in[2];
    x  = (const float*)d_in[3];
  } else {
    x  = (const float*)d_in[0];
    bw = (const float*)d_in[1];
    bb = (const float*)d_in[2];
    sw = (const float*)d_in[3];
  }
  float* out = (float*)d_out;
  const int rows = (in_sizes[0] == OUT_F) ? in_sizes[3] / IN_F : in_sizes[0] / IN_F;

  if (ws_size >= WS_NEEDED && d_ws != nullptr && (rows % BM) == 0) {
    hipLaunchKernelGGL(wprep, dim3(2048), dim3(256), 0, stream, bw, sw, (char*)d_ws);
    dim3 grid(NBLK, rows / BM);          // N fastest -> per-XCD weight-panel locality
    hipLaunchKernelGGL(kan_fast, grid, dim3(512), 0, stream,
                       x, bb, (const char*)d_ws, out);
  } else {
    dim3 grid(rows / 128, OUT_F / 128);
    hipLaunchKernelGGL(kan_slow, grid, dim3(256), 0, stream, x, bw, bb, sw, out);
  }
}